// Round 7
// baseline (1526.251 us; speedup 1.0000x reference)
//
#include <hip/hip_runtime.h>
#include <math.h>

#define BATCH 8
#define SEQ   2048
#define TOK   (BATCH*SEQ)     // 16384
#define CIN   32
#define DM    512
#define DFF   2048
#define NH    8
#define HD    64
#define NSAMP 24
#define NTOP  24
#define EPS   1e-5f
#define QKVLD 1536

typedef unsigned int u32;
typedef unsigned short u16;
typedef unsigned long long u64;
typedef __attribute__((ext_vector_type(8))) short short8;
typedef __attribute__((ext_vector_type(4))) float floatx4;

__device__ __forceinline__ void async16(const void* g, void* l) {
    __builtin_amdgcn_global_load_lds((const __attribute__((address_space(1))) u32*)g,
                                     (__attribute__((address_space(3))) u32*)l, 16, 0, 0);
}
__device__ __forceinline__ u16 bf16rn(float f) {
    u32 u = __float_as_uint(f);
    return (u16)((u + 0x7fffu + ((u >> 16) & 1u)) >> 16);
}

// ---------------- Threefry-2x32 ----------------
__device__ __forceinline__ void tf_round(unsigned &x0, unsigned &x1, int r) {
    x0 += x1;
    x1 = (x1 << r) | (x1 >> (32 - r));
    x1 ^= x0;
}
__device__ __forceinline__ void threefry(unsigned k0, unsigned k1,
                                         unsigned c0, unsigned c1,
                                         unsigned &o0, unsigned &o1) {
    unsigned ks0 = k0, ks1 = k1, ks2 = k0 ^ k1 ^ 0x1BD11BDAu;
    unsigned x0 = c0 + ks0, x1 = c1 + ks1;
    tf_round(x0,x1,13); tf_round(x0,x1,15); tf_round(x0,x1,26); tf_round(x0,x1,6);
    x0 += ks1; x1 += ks2 + 1u;
    tf_round(x0,x1,17); tf_round(x0,x1,29); tf_round(x0,x1,16); tf_round(x0,x1,24);
    x0 += ks2; x1 += ks0 + 2u;
    tf_round(x0,x1,13); tf_round(x0,x1,15); tf_round(x0,x1,26); tf_round(x0,x1,6);
    x0 += ks0; x1 += ks1 + 3u;
    tf_round(x0,x1,17); tf_round(x0,x1,29); tf_round(x0,x1,16); tf_round(x0,x1,24);
    x0 += ks1; x1 += ks2 + 4u;
    tf_round(x0,x1,13); tf_round(x0,x1,15); tf_round(x0,x1,26); tf_round(x0,x1,6);
    x0 += ks2; x1 += ks0 + 5u;
    o0 = x0; o1 = x1;
}

__global__ void sample_kernel(int* __restrict__ idx_sample) {
    const int HALF = (SEQ * NSAMP) / 2;  // 24576
    int p = blockIdx.x * blockDim.x + threadIdx.x;
    int li = blockIdx.y;
    if (p >= HALF) return;
    unsigned f0, f1;
    threefry(0u, 42u, 0u, (unsigned)li, f0, f1);
    unsigned a0, a1, b0, b1;
    threefry(f0, f1, 0u, 2u, a0, a1);
    threefry(f0, f1, 1u, 3u, b0, b1);
    unsigned o0, o1;
    threefry(a1, b1, (unsigned)p, (unsigned)(p + HALF), o0, o1);
    idx_sample[li * SEQ * NSAMP + p]        = (int)(o0 & (SEQ - 1));
    idx_sample[li * SEQ * NSAMP + p + HALF] = (int)(o1 & (SEQ - 1));
}

// ---------------- input layernorm over C_IN=32 ----------------
__global__ __launch_bounds__(256) void ln_in_kernel(const float* __restrict__ x,
        const float* __restrict__ g, const float* __restrict__ b,
        float* __restrict__ out) {
    int t = blockIdx.x * blockDim.x + threadIdx.x;
    if (t >= TOK) return;
    const float* xr = x + (size_t)t * CIN;
    float vals[CIN];
    float s = 0.f;
#pragma unroll
    for (int c = 0; c < CIN; c++) { vals[c] = xr[c]; s += vals[c]; }
    float m = s * (1.f / CIN);
    float v = 0.f;
#pragma unroll
    for (int c = 0; c < CIN; c++) { float d = vals[c] - m; v += d * d; }
    v *= (1.f / CIN);
    float inv = rsqrtf(v + EPS);
    float* orow = out + (size_t)t * CIN;
#pragma unroll
    for (int c = 0; c < CIN; c++) orow[c] = (vals[c] - m) * inv * g[c] + b[c];
}

// ---------------- im2col (wrap pad), fp32: A[t][j], j=w*32+c ----------------
__global__ __launch_bounds__(128) void im2col_kernel(const float* __restrict__ xln,
        float* __restrict__ a) {
    int t = blockIdx.x;
    int j = threadIdx.x;
    if (j >= 96) return;
    int b = t >> 11, l = t & 2047;
    int w = j >> 5, c = j & 31;
    int lw = (l - 1 + w + SEQ) & 2047;
    a[(size_t)t * 96 + j] = xln[(((size_t)b << 11) | lw) * CIN + c];
}

// ---------------- W_tok transpose + split to interleaved u32: wt[o][j] ----------------
__global__ __launch_bounds__(256) void wtok_split(const float* __restrict__ Wtok,
        u32* __restrict__ wt) {
    int e = blockIdx.x * 256 + threadIdx.x;  // < 49152
    int o = e / 96, j = e % 96;
    float f = Wtok[(size_t)j * DM + o];
    u16 hb = bf16rn(f);
    u16 lb = bf16rn(f - __uint_as_float((u32)hb << 16));
    wt[e] = (u32)hb | ((u32)lb << 16);
}

// ---------------- positional embedding table pe[l][o] ----------------
__global__ __launch_bounds__(256) void pe_kernel(float* __restrict__ pe) {
    int e = blockIdx.x * 256 + threadIdx.x;  // < 1048576
    int l = e >> 9, o = e & 511;
    const float c1 = -0.017988946039016f;  // -ln(10000)/512
    int i2 = o & ~1;
    float div = expf((float)i2 * c1);
    float arg = (float)l * div;
    pe[e] = (o & 1) ? cosf(arg) : sinf(arg);
}

// ---------------- rsd[t][o] = pe[l][o] + tf[t]·Wtime[o] ----------------
__global__ __launch_bounds__(256) void rsd_kernel(const float* __restrict__ pe,
        const float* __restrict__ tfeat, const float* __restrict__ Wtime,
        float* __restrict__ rsd) {
    int t = blockIdx.x, tid = threadIdx.x;
    int l = t & 2047;
    float t0 = tfeat[(size_t)t * 4], t1 = tfeat[(size_t)t * 4 + 1];
    float t2 = tfeat[(size_t)t * 4 + 2], t3 = tfeat[(size_t)t * 4 + 3];
    for (int o = tid; o < DM; o += 256) {
        rsd[(size_t)t * DM + o] = pe[l * DM + o]
            + t0 * Wtime[o * 4] + t1 * Wtime[o * 4 + 1]
            + t2 * Wtime[o * 4 + 2] + t3 * Wtime[o * 4 + 3];
    }
}

// ---------------- weight split: fp32 -> interleaved (bf16_h | bf16_l<<16) ----------------
__global__ __launch_bounds__(256) void split_weights(const float* __restrict__ Wq,
        const float* __restrict__ Wk, const float* __restrict__ Wv,
        const float* __restrict__ Wo, const float* __restrict__ W1,
        const float* __restrict__ W2, u32* __restrict__ out) {
    int i = blockIdx.x * 256 + threadIdx.x;  // < 3145728
    const float* src; int off;
    if (i < 1048576) {
        src = (i < 262144) ? Wq : (i < 524288) ? Wk : (i < 786432) ? Wv : Wo;
        off = i & 262143;
    } else if (i < 2097152) { src = W1; off = i - 1048576; }
    else { src = W2; off = i - 2097152; }
    float f = src[off];
    u16 h = bf16rn(f);
    u16 l = bf16rn(f - __uint_as_float((u32)h << 16));
    out[i] = (u32)h | ((u32)l << 16);
}

__global__ void concat_bias(const float* __restrict__ bq, const float* __restrict__ bk,
                            const float* __restrict__ bv, float* __restrict__ o) {
    int i = blockIdx.x * 256 + threadIdx.x;  // < 1536
    o[i] = (i < 512) ? bq[i] : (i < 1024) ? bk[i - 512] : bv[i - 1024];
}

// ---------------- split-bf16 MFMA GEMM: C = A[MxK]*W[NxK]^T + bias (+res)(+relu) ----------
// A: fp32, split on the fly (overlaps W DMA).  Wp: interleaved (h|l<<16) u32.
// launch_bounds(256,3): 3 blocks/CU (LDS 36.9KB*3=110KB, ~170 regs/wave budget — no spill)
template<bool RELU, bool RES>
__global__ __launch_bounds__(256, 3) void gemm_split(const float* __restrict__ A,
        const u32* __restrict__ Wp, const float* __restrict__ bias,
        const float* __restrict__ Rsd, float* __restrict__ C,
        int ldc, int K, int lda) {
    __shared__ alignas(16) u16 AhS[128 * 40];   // padded stride 40
    __shared__ alignas(16) u16 AlS[128 * 40];
    __shared__ alignas(16) u32 Wt[4 * 128 * 8]; // [kchunk8][row][8 words]
    const int tid = threadIdx.x;
    const int m0 = blockIdx.y * 128, n0 = blockIdx.x * 128;
    const int lane = tid & 63, wv = tid >> 6;
    const int wm = wv >> 1, wn = wv & 1;
    const int fr = lane & 15, q = lane >> 4;

    floatx4 acc[4][4] = {};

    const int arow = tid >> 1, ahalf = tid & 1;
    const float* abase = A + (size_t)(m0 + arow) * lda + ahalf * 16;
    const u32* wbase = Wp + (size_t)(n0 + (tid >> 1)) * K + (tid & 1) * 4;
    char* wdst = (char*)Wt + tid * 16;
    u16* ahw = &AhS[arow * 40 + ahalf * 16];
    u16* alw = &AlS[arow * 40 + ahalf * 16];

    for (int k0 = 0; k0 < K; k0 += 32) {
        // --- stage W tile (async DMA to LDS, chunked 8-elem layout) ---
#pragma unroll
        for (int i = 0; i < 4; i++)
            async16(wbase + k0 + i * 8, wdst + i * 4096);
        // --- stage A tile: fp32 load, split to bf16 h/l, LDS write (overlaps DMA) ---
        const float* ap = abase + k0;
        float f[16];
        *(float4*)&f[0]  = *(const float4*)(ap);
        *(float4*)&f[4]  = *(const float4*)(ap + 4);
        *(float4*)&f[8]  = *(const float4*)(ap + 8);
        *(float4*)&f[12] = *(const float4*)(ap + 12);
        short8 h0, h1, l0, l1;
#pragma unroll
        for (int j = 0; j < 8; j++) {
            u16 hb = bf16rn(f[j]);
            float r = f[j] - __uint_as_float((u32)hb << 16);
            h0[j] = (short)hb; l0[j] = (short)bf16rn(r);
            u16 hb2 = bf16rn(f[j + 8]);
            float r2 = f[j + 8] - __uint_as_float((u32)hb2 << 16);
            h1[j] = (short)hb2; l1[j] = (short)bf16rn(r2);
        }
        *(short8*)(ahw)     = h0;  *(short8*)(ahw + 8) = h1;
        *(short8*)(alw)     = l0;  *(short8*)(alw + 8) = l1;
        __syncthreads();
        // --- fragments + MFMA ---
        short8 ah[4], al[4];
#pragma unroll
        for (int mi = 0; mi < 4; mi++) {
            int off = (wm * 64 + mi * 16 + fr) * 40 + q * 8;
            ah[mi] = *(const short8*)&AhS[off];
            al[mi] = *(const short8*)&AlS[off];
        }
#pragma unroll
        for (int ni = 0; ni < 4; ni++) {
            const u32* cell = &Wt[(size_t)(q * 128 + wn * 64 + ni * 16 + fr) * 8];
            union { u32 u[4]; short8 s; } wh, wl;
            u32 w0 = cell[0], w1 = cell[1], w2 = cell[2], w3 = cell[3];
            u32 w4 = cell[4], w5 = cell[5], w6 = cell[6], w7 = cell[7];
            wh.u[0] = (w0 & 0xffffu) | (w1 << 16);
            wh.u[1] = (w2 & 0xffffu) | (w3 << 16);
            wh.u[2] = (w4 & 0xffffu) | (w5 << 16);
            wh.u[3] = (w6 & 0xffffu) | (w7 << 16);
            wl.u[0] = (w0 >> 16) | (w1 & 0xffff0000u);
            wl.u[1] = (w2 >> 16) | (w3 & 0xffff0000u);
            wl.u[2] = (w4 >> 16) | (w5 & 0xffff0000u);
            wl.u[3] = (w6 >> 16) | (w7 & 0xffff0000u);
#pragma unroll
            for (int mi = 0; mi < 4; mi++) {
                acc[mi][ni] = __builtin_amdgcn_mfma_f32_16x16x32_bf16(ah[mi], wh.s, acc[mi][ni], 0, 0, 0);
                acc[mi][ni] = __builtin_amdgcn_mfma_f32_16x16x32_bf16(ah[mi], wl.s, acc[mi][ni], 0, 0, 0);
                acc[mi][ni] = __builtin_amdgcn_mfma_f32_16x16x32_bf16(al[mi], wh.s, acc[mi][ni], 0, 0, 0);
            }
        }
        __syncthreads();
    }
    // --- epilogue ---
#pragma unroll
    for (int ni = 0; ni < 4; ni++) {
        int col = n0 + wn * 64 + ni * 16 + fr;
        float bv = bias[col];
#pragma unroll
        for (int mi = 0; mi < 4; mi++) {
            int row = m0 + wm * 64 + mi * 16 + q * 4;
#pragma unroll
            for (int r = 0; r < 4; r++) {
                size_t idx = (size_t)(row + r) * ldc + col;
                float v = acc[mi][ni][r] + bv;
                if (RES) v += Rsd[idx];
                if (RELU) v = fmaxf(v, 0.f);
                C[idx] = v;
            }
        }
    }
}

// ---------------- M = max(QK_sample) - sum/L : one wave per (b,h,l) ----------------
__global__ __launch_bounds__(256) void qk_sample_kernel(const float* __restrict__ qkv,
        const int* __restrict__ idx_sample, float* __restrict__ Mout) {
    int r = (blockIdx.x * 256 + threadIdx.x) >> 6;
    int lane = threadIdx.x & 63;
    if (r >= BATCH * NH * SEQ) return;
    int b = r / (NH * SEQ);
    int head = (r / SEQ) % NH;
    int l = r % SEQ;
    int sidx = lane >> 4, dc = lane & 15;
    const float* qrow = qkv + ((size_t)(b * SEQ + l)) * QKVLD + head * HD + dc * 4;
    float4 qf = *(const float4*)qrow;
    int myidx = (lane < NSAMP) ? idx_sample[l * NSAMP + lane] : 0;
    const float* kbase = qkv + (size_t)b * SEQ * QKVLD + 512 + head * HD + dc * 4;
    float mx = -INFINITY, sm = 0.f;
#pragma unroll
    for (int p = 0; p < 6; p++) {
        int s = p * 4 + sidx;
        int kidx = __shfl(myidx, s);
        float4 kf = *(const float4*)(kbase + (size_t)kidx * QKVLD);
        float part = qf.x * kf.x + qf.y * kf.y + qf.z * kf.z + qf.w * kf.w;
        part += __shfl_xor(part, 1);
        part += __shfl_xor(part, 2);
        part += __shfl_xor(part, 4);
        part += __shfl_xor(part, 8);
        mx = fmaxf(mx, part);
        sm += part;
    }
    mx = fmaxf(mx, __shfl_xor(mx, 16));
    mx = fmaxf(mx, __shfl_xor(mx, 32));
    sm += __shfl_xor(sm, 16);
    sm += __shfl_xor(sm, 32);
    if (lane == 0) Mout[r] = mx - sm * (1.f / SEQ);
}

// ---------------- top-24 two-stage: packed u64 keys, exact (idx unique) ----------------
__device__ __forceinline__ u64 pack_key(float v, int idx) {
    u32 u = __float_as_uint(v);
    u32 m = (u & 0x80000000u) ? ~u : (u | 0x80000000u);
    return ((u64)m << 32) | (u32)(~(u32)idx);
}

__global__ __launch_bounds__(256) void topk_part(const float* __restrict__ Mbuf,
        u64* __restrict__ cand) {
    __shared__ u64 vals[256];
    __shared__ u64 red[256];
    int bh = blockIdx.x, chunk = blockIdx.y;
    int tid = threadIdx.x;
    int l = chunk * 256 + tid;
    vals[tid] = pack_key(Mbuf[(size_t)bh * SEQ + l], l);
    __syncthreads();
    for (int it = 0; it < NTOP; it++) {
        red[tid] = vals[tid];
        __syncthreads();
        for (int s = 128; s > 0; s >>= 1) {
            if (tid < s) { u64 o = red[tid + s]; if (o > red[tid]) red[tid] = o; }
            __syncthreads();
        }
        u64 win = red[0];
        if (vals[tid] == win) vals[tid] = 0;
        if (tid == 0) cand[((size_t)bh * 8 + chunk) * NTOP + it] = win;
        __syncthreads();
    }
}

__global__ __launch_bounds__(256) void topk_merge(const u64* __restrict__ cand,
        int* __restrict__ idx_top) {
    __shared__ u64 vals[256];
    __shared__ u64 red[256];
    int bh = blockIdx.x;
    int tid = threadIdx.x;
    vals[tid] = (tid < 8 * NTOP) ? cand[(size_t)bh * 8 * NTOP + tid] : 0;
    __syncthreads();
    for (int it = 0; it < NTOP; it++) {
        red[tid] = vals[tid];
        __syncthreads();
        for (int s = 128; s > 0; s >>= 1) {
            if (tid < s) { u64 o = red[tid + s]; if (o > red[tid]) red[tid] = o; }
            __syncthreads();
        }
        u64 win = red[0];
        if (vals[tid] == win) vals[tid] = 0;
        if (tid == 0) idx_top[bh * NTOP + it] = (int)(~(u32)(win & 0xffffffffull) & (SEQ - 1));
        __syncthreads();
    }
}

// ---------------- V mean over keys per (b,h) ----------------
__global__ __launch_bounds__(256) void vmean_kernel(const float* __restrict__ qkv,
        float* __restrict__ vmean) {
    __shared__ float red[256];
    int bh = blockIdx.x, slab = blockIdx.y;
    int b = bh >> 3, head = bh & 7;
    int seg = threadIdx.x >> 6, d = threadIdx.x & 63;
    int base_row = slab * 256 + seg * 64;
    float s = 0.f;
    for (int r = 0; r < 64; r++)
        s += qkv[((size_t)(b * SEQ + base_row + r)) * QKVLD + 1024 + head * HD + d];
    red[threadIdx.x] = s;
    __syncthreads();
    if (threadIdx.x < 128) red[threadIdx.x] += red[threadIdx.x + 128];
    __syncthreads();
    if (threadIdx.x < 64) {
        float t = red[threadIdx.x] + red[threadIdx.x + 64];
        atomicAdd(&vmean[bh * HD + d], t * (1.f / SEQ));
    }
}

// ---------------- fill context with V-mean ----------------
__global__ void fillctx_kernel(const float* __restrict__ vmean, float* __restrict__ out) {
    int e = blockIdx.x * 256 + threadIdx.x;
    int c = e & 511;
    int b = e >> 20;
    out[e] = vmean[(((b << 3) | (c >> 6)) << 6) + (c & 63)];
}

// ---------------- flash-style sparse attention: block = (b*h, key-slab of 512) ----------------
__global__ __launch_bounds__(256) void spattn_flash(const float* __restrict__ qkv,
        const int* __restrict__ idx_top, float* __restrict__ opart,
        float* __restrict__ mspart) {
    __shared__ float KtT[64][65];   // transposed: [dim][key]
    __shared__ float Vt[64][65];    // [key][dim]
    __shared__ float Qs[24][64];
    __shared__ float Ps[24][66];
    int bh = blockIdx.x, slab = blockIdx.y;
    int b = bh >> 3, h = bh & 7;
    int tid = threadIdx.x;
    int wv = tid >> 6, lane = tid & 63;
    for (int i = tid; i < NTOP * 64; i += 256) {
        int u = i >> 6, d = i & 63;
        int qi = idx_top[bh * NTOP + u];
        Qs[u][d] = qkv[((size_t)(b * SEQ + qi)) * QKVLD + h * HD + d];
    }
    float m[6], s[6], o[6], alpha[6];
#pragma unroll
    for (int j = 0; j < 6; j++) { m[j] = -INFINITY; s[j] = 0.f; o[j] = 0.f; }
    int key0 = slab * 512;
    int sr = tid >> 2, sc0 = (tid & 3) * 16;
    for (int t = 0; t < 8; t++) {
        int kbase = key0 + t * 64;
        __syncthreads();
        const float* kr = qkv + ((size_t)(b * SEQ + kbase + sr)) * QKVLD + 512 + h * HD + sc0;
        const float* vr = qkv + ((size_t)(b * SEQ + kbase + sr)) * QKVLD + 1024 + h * HD + sc0;
        float kf[16], vf[16];
        *(float4*)&kf[0]  = *(const float4*)(kr);
        *(float4*)&kf[4]  = *(const float4*)(kr + 4);
        *(float4*)&kf[8]  = *(const float4*)(kr + 8);
        *(float4*)&kf[12] = *(const float4*)(kr + 12);
        *(float4*)&vf[0]  = *(const float4*)(vr);
        *(float4*)&vf[4]  = *(const float4*)(vr + 4);
        *(float4*)&vf[8]  = *(const float4*)(vr + 8);
        *(float4*)&vf[12] = *(const float4*)(vr + 12);
#pragma unroll
        for (int i = 0; i < 16; i++) {
            KtT[sc0 + i][sr] = kf[i];
            Vt[sr][sc0 + i] = vf[i];
        }
        __syncthreads();
        float dot[6] = {};
#pragma unroll
        for (int d = 0; d < 64; d++) {
            float kv = KtT[d][lane];
#pragma unroll
            for (int j = 0; j < 6; j++) dot[j] += Qs[wv * 6 + j][d] * kv;
        }
#pragma unroll
        for (int j = 0; j < 6; j++) {
            float sc = dot[j] * 0.125f;
            float tmax = sc;
            for (int off = 32; off > 0; off >>= 1) tmax = fmaxf(tmax, __shfl_xor(tmax, off));
            float mn = fmaxf(m[j], tmax);
            float p = __expf(sc - mn);
            float psum = p;
            for (int off = 32; off > 0; off >>= 1) psum += __shfl_xor(psum, off);
            alpha[j] = __expf(m[j] - mn);
            s[j] = s[j] * alpha[j] + psum;
            m[j] = mn;
            Ps[wv * 6 + j][lane] = p;
        }
        float pv[6] = {};
#pragma unroll
        for (int key = 0; key < 64; key++) {
            float vvv = Vt[key][lane];
#pragma unroll
            for (int j = 0; j < 6; j++) pv[j] += Ps[wv * 6 + j][key] * vvv;
        }
#pragma unroll
        for (int j = 0; j < 6; j++) o[j] = o[j] * alpha[j] + pv[j];
    }
    float* ob = opart + ((size_t)(bh * 4 + slab)) * NTOP * 64;
#pragma unroll
    for (int j = 0; j < 6; j++) ob[(wv * 6 + j) * 64 + lane] = o[j];
    if (lane == 0) {
        float* ms = mspart + ((size_t)(bh * 4 + slab)) * NTOP * 2;
#pragma unroll
        for (int j = 0; j < 6; j++) {
            ms[(wv * 6 + j) * 2]     = m[j];
            ms[(wv * 6 + j) * 2 + 1] = s[j];
        }
    }
}

// ---------------- merge 4 slab partials, scatter into context ----------------
__global__ __launch_bounds__(256) void spattn_combine(const float* __restrict__ opart,
        const float* __restrict__ mspart, const int* __restrict__ idx_top,
        float* __restrict__ out) {
    __shared__ float wgt[4][NTOP];
    int bh = blockIdx.x;
    int b = bh >> 3, h = bh & 7;
    int tid = threadIdx.x;
    if (tid < NTOP) {
        float mv[4], sv[4];
        float M = -INFINITY;
#pragma unroll
        for (int sl = 0; sl < 4; sl++) {
            mv[sl] = mspart[((size_t)(bh * 4 + sl)) * NTOP * 2 + tid * 2];
            sv[sl] = mspart[((size_t)(bh * 4 + sl)) * NTOP * 2 + tid * 2 + 1];
            M = fmaxf(M, mv[sl]);
        }
        float S = 0.f;
#pragma unroll
        for (int sl = 0; sl < 4; sl++) S += sv[sl] * __expf(mv[sl] - M);
        float invS = 1.f / S;
#pragma unroll
        for (int sl = 0; sl < 4; sl++) wgt[sl][tid] = __expf(mv[sl] - M) * invS;
    }
    __syncthreads();
    for (int i = tid; i < NTOP * 64; i += 256) {
        int u = i >> 6, d = i & 63;
        float val = 0.f;
#pragma unroll
        for (int sl = 0; sl < 4; sl++)
            val += wgt[sl][u] * opart[(((size_t)(bh * 4 + sl)) * NTOP + u) * 64 + d];
        int qi = idx_top[bh * NTOP + u];
        out[((size_t)(b * SEQ + qi)) * DM + h * HD + d] = val;
    }
}

// ---------------- layernorm over DM=512 ----------------
__global__ __launch_bounds__(256) void ln_kernel(const float* src,
        const float* __restrict__ g, const float* __restrict__ b, float* dst) {
    __shared__ float red[256];
    int t = blockIdx.x, tid = threadIdx.x;
    const float* xr = src + (size_t)t * DM;
    float x0 = xr[tid], x1 = xr[tid + 256];
    red[tid] = x0 + x1; __syncthreads();
    for (int s = 128; s > 0; s >>= 1) { if (tid < s) red[tid] += red[tid + s]; __syncthreads(); }
    float m = red[0] * (1.f / DM);
    __syncthreads();
    float d0 = x0 - m, d1 = x1 - m;
    red[tid] = d0 * d0 + d1 * d1; __syncthreads();
    for (int s = 128; s > 0; s >>= 1) { if (tid < s) red[tid] += red[tid + s]; __syncthreads(); }
    float inv = rsqrtf(red[0] * (1.f / DM) + EPS);
    float* dr = dst + (size_t)t * DM;
    dr[tid] = d0 * inv * g[tid] + b[tid];
    dr[tid + 256] = d1 * inv * g[tid + 256] + b[tid + 256];
}

// ---------------- prediction head on last token ----------------
__global__ __launch_bounds__(256) void head_kernel(const float* __restrict__ hfin,
        const float* __restrict__ Wpre, const float* __restrict__ bpre,
        const float* __restrict__ Wfc, const float* __restrict__ bfc,
        float* __restrict__ out) {
    __shared__ float last[DM];
    __shared__ float red[256];
    int b = blockIdx.x, tid = threadIdx.x;
    const float* hr = hfin + ((size_t)(b * SEQ + SEQ - 1)) * DM;
    last[tid] = hr[tid];
    last[tid + 256] = hr[tid + 256];
    __syncthreads();
    float acc = bpre[tid];
    for (int c = 0; c < DM; c++) acc += last[c] * Wpre[tid * DM + c];
    acc = fmaxf(acc, 0.f);
    red[tid] = acc * Wfc[tid];
    __syncthreads();
    for (int s = 128; s > 0; s >>= 1) { if (tid < s) red[tid] += red[tid + s]; __syncthreads(); }
    if (tid == 0) out[b] = red[0] + bfc[0];
}

extern "C" void kernel_launch(void* const* d_in, const int* in_sizes, int n_in,
                              void* d_out, int out_size, void* d_ws, size_t ws_size,
                              hipStream_t stream) {
    (void)in_sizes; (void)n_in; (void)out_size; (void)ws_size;
    const float* x      = (const float*)d_in[0];
    const float* tfeat  = (const float*)d_in[1];
    const float* g_in   = (const float*)d_in[2];
    const float* b_in   = (const float*)d_in[3];
    const float* W_tok  = (const float*)d_in[4];
    const float* W_time = (const float*)d_in[5];
    const float* b_time = (const float*)d_in[6];
    const float* Wq     = (const float*)d_in[7];
    const float* bq     = (const float*)d_in[8];
    const float* Wk     = (const float*)d_in[9];
    const float* bk     = (const float*)d_in[10];
    const float* Wv     = (const float*)d_in[11];
    const float* bv     = (const float*)d_in[12];
    const float* Wo     = (const float*)d_in[13];
    const float* bo     = (const float*)d_in[14];
    const float* W1     = (const float*)d_in[15];
    const float* b1     = (const float*)d_in[16];
    const float* W2     = (const float*)d_in[17];
    const float* b2     = (const float*)d_in[18];
    const float* g1     = (const float*)d_in[19];
    const float* be1    = (const float*)d_in[20];
    const float* g2     = (const float*)d_in[21];
    const float* be2    = (const float*)d_in[22];
    const float* g_enc  = (const float*)d_in[23];
    const float* b_enc  = (const float*)d_in[24];
    const float* W_pre  = (const float*)d_in[25];
    const float* b_pre  = (const float*)d_in[26];
    const float* W_fc   = (const float*)d_in[27];
    const float* b_fc   = (const float*)d_in[28];
    float* out = (float*)d_out;

    char* ws = (char*)d_ws;
    float* h    = (float*)(ws);                      // 33.5 MB fp32 residual
    float* tmp  = (float*)(ws + 33554432);           // 33.5 MB fp32
    char*  bigc = ws + 67108864;                     // 134.2 MB multi-use
    float* big  = (float*)bigc;                      // qkv [TOK][1536] fp32 / FFN mid
    // embed-stage overlays inside big:
    float* xln  = (float*)(bigc);                    // 2 MB
    float* acv  = (float*)(bigc + 2097152);          // im2col [TOK][96] fp32, 6.3 MB
    float* pe   = (float*)(bigc + 8388608);          // 4 MB
    float* rsd  = (float*)(bigc + 12582912);         // 33.5 MB
    u32*   wtok = (u32*)(bigc + 46137344);           // W_tok interleaved [512][96]
    u32*   wpair      = (u32*)(ws + 201326592);      // 12.6 MB per-layer weights
    float* Mbuf       = (float*)(ws + 213909504);    // 0.5 MB
    float* vmean      = (float*)(ws + 214433792);
    int*   idx_sample = (int*)(ws + 214450176);
    int*   idx_top    = (int*)(ws + 214843392);
    float* biasqkv    = (float*)(ws + 214849536);
    u64*   cand       = (u64*)(ws + 214855680);      // 98 KB
    float* opart      = (float*)(ws + 214953984);    // 1.57 MB
    float* mspart     = (float*)(ws + 216526848);    // 48 KB

    ln_in_kernel<<<TOK / 256, 256, 0, stream>>>(x, g_in, b_in, xln);
    im2col_kernel<<<TOK, 128, 0, stream>>>(xln, acv);
    wtok_split<<<192, 256, 0, stream>>>(W_tok, wtok);
    pe_kernel<<<4096, 256, 0, stream>>>(pe);
    rsd_kernel<<<TOK, 256, 0, stream>>>(pe, tfeat, W_time, rsd);
    sample_kernel<<<dim3(96, 2), 256, 0, stream>>>(idx_sample);

    // conv-as-GEMM: h = im2col @ W_tok^T + b_time + (pe + time emb)
    gemm_split<false, true><<<dim3(4, 128), 256, 0, stream>>>(
        acv, wtok, b_time, rsd, h, DM, 96, 96);

    const u32* wqkv_p = wpair;                // rows 0..1535 = Wq;Wk;Wv
    const u32* wo_p = wpair + 786432;
    const u32* w1_p = wpair + 1048576;
    const u32* w2_p = wpair + 2097152;

    for (int li = 0; li < 2; li++) {
        split_weights<<<12288, 256, 0, stream>>>(
            Wq + (size_t)li * DM * DM, Wk + (size_t)li * DM * DM,
            Wv + (size_t)li * DM * DM, Wo + (size_t)li * DM * DM,
            W1 + (size_t)li * DFF * DM, W2 + (size_t)li * DM * DFF, wpair);
        concat_bias<<<6, 256, 0, stream>>>(bq + (size_t)li * DM, bk + (size_t)li * DM,
                                           bv + (size_t)li * DM, biasqkv);

        const float* bo_i = bo + (size_t)li * DM;
        const float* b1_i = b1 + (size_t)li * DFF;
        const float* b2_i = b2 + (size_t)li * DM;
        const float* g1_i = g1 + (size_t)li * DM;
        const float* be1_i = be1 + (size_t)li * DM;
        const float* g2_i = g2 + (size_t)li * DM;
        const float* be2_i = be2 + (size_t)li * DM;

        // fused QKV: [TOK][1536] fp32
        gemm_split<false, false><<<dim3(QKVLD / 128, TOK / 128), 256, 0, stream>>>(
            h, wqkv_p, biasqkv, nullptr, big, QKVLD, DM, DM);

        qk_sample_kernel<<<(BATCH * NH * SEQ) / 4, 256, 0, stream>>>(
            big, idx_sample + li * SEQ * NSAMP, Mbuf);
        topk_part<<<dim3(BATCH * NH, 8), 256, 0, stream>>>(Mbuf, cand);
        topk_merge<<<BATCH * NH, 256, 0, stream>>>(cand, idx_top);
        hipMemsetAsync(vmean, 0, BATCH * NH * HD * sizeof(float), stream);
        vmean_kernel<<<dim3(BATCH * NH, 8), 256, 0, stream>>>(big, vmean);
        fillctx_kernel<<<(TOK * DM) / 256, 256, 0, stream>>>(vmean, tmp);
        spattn_flash<<<dim3(BATCH * NH, 4), 256, 0, stream>>>(big, idx_top, opart, mspart);
        spattn_combine<<<BATCH * NH, 256, 0, stream>>>(opart, mspart, idx_top, tmp);

        // Wo with residual into h
        gemm_split<false, true><<<dim3(DM / 128, TOK / 128), 256, 0, stream>>>(
            tmp, wo_p, bo_i, h, h, DM, DM, DM);
        ln_kernel<<<TOK, 256, 0, stream>>>(h, g1_i, be1_i, h);

        // FFN full-width
        gemm_split<true, false><<<dim3(DFF / 128, TOK / 128), 256, 0, stream>>>(
            h, w1_p, b1_i, nullptr, big, DFF, DM, DM);
        gemm_split<false, true><<<dim3(DM / 128, TOK / 128), 256, 0, stream>>>(
            big, w2_p, b2_i, h, tmp, DM, DFF, DFF);
        ln_kernel<<<TOK, 256, 0, stream>>>(tmp, g2_i, be2_i, h);
    }

    ln_kernel<<<TOK, 256, 0, stream>>>(h, g_enc, b_enc, tmp);
    head_kernel<<<BATCH, 256, 0, stream>>>(tmp, W_pre, b_pre, W_fc, b_fc, out);
}

// Round 8
// 1499.491 us; speedup vs baseline: 1.0178x; 1.0178x over previous
//
#include <hip/hip_runtime.h>
#include <math.h>

#define BATCH 8
#define SEQ   2048
#define TOK   (BATCH*SEQ)     // 16384
#define CIN   32
#define DM    512
#define DFF   2048
#define NH    8
#define HD    64
#define NSAMP 24
#define NTOP  24
#define EPS   1e-5f
#define QKVLD 1536

typedef unsigned int u32;
typedef unsigned short u16;
typedef unsigned long long u64;
typedef __attribute__((ext_vector_type(8))) short short8;
typedef __attribute__((ext_vector_type(4))) float floatx4;

__device__ __forceinline__ void async16(const void* g, void* l) {
    __builtin_amdgcn_global_load_lds((const __attribute__((address_space(1))) u32*)g,
                                     (__attribute__((address_space(3))) u32*)l, 16, 0, 0);
}
__device__ __forceinline__ u16 bf16rn(float f) {
    u32 u = __float_as_uint(f);
    return (u16)((u + 0x7fffu + ((u >> 16) & 1u)) >> 16);
}

// ---------------- Threefry-2x32 ----------------
__device__ __forceinline__ void tf_round(unsigned &x0, unsigned &x1, int r) {
    x0 += x1;
    x1 = (x1 << r) | (x1 >> (32 - r));
    x1 ^= x0;
}
__device__ __forceinline__ void threefry(unsigned k0, unsigned k1,
                                         unsigned c0, unsigned c1,
                                         unsigned &o0, unsigned &o1) {
    unsigned ks0 = k0, ks1 = k1, ks2 = k0 ^ k1 ^ 0x1BD11BDAu;
    unsigned x0 = c0 + ks0, x1 = c1 + ks1;
    tf_round(x0,x1,13); tf_round(x0,x1,15); tf_round(x0,x1,26); tf_round(x0,x1,6);
    x0 += ks1; x1 += ks2 + 1u;
    tf_round(x0,x1,17); tf_round(x0,x1,29); tf_round(x0,x1,16); tf_round(x0,x1,24);
    x0 += ks2; x1 += ks0 + 2u;
    tf_round(x0,x1,13); tf_round(x0,x1,15); tf_round(x0,x1,26); tf_round(x0,x1,6);
    x0 += ks0; x1 += ks1 + 3u;
    tf_round(x0,x1,17); tf_round(x0,x1,29); tf_round(x0,x1,16); tf_round(x0,x1,24);
    x0 += ks1; x1 += ks2 + 4u;
    tf_round(x0,x1,13); tf_round(x0,x1,15); tf_round(x0,x1,26); tf_round(x0,x1,6);
    x0 += ks2; x1 += ks0 + 5u;
    o0 = x0; o1 = x1;
}

__global__ void sample_kernel(int* __restrict__ idx_sample) {
    const int HALF = (SEQ * NSAMP) / 2;  // 24576
    int p = blockIdx.x * blockDim.x + threadIdx.x;
    int li = blockIdx.y;
    if (p >= HALF) return;
    unsigned f0, f1;
    threefry(0u, 42u, 0u, (unsigned)li, f0, f1);
    unsigned a0, a1, b0, b1;
    threefry(f0, f1, 0u, 2u, a0, a1);
    threefry(f0, f1, 1u, 3u, b0, b1);
    unsigned o0, o1;
    threefry(a1, b1, (unsigned)p, (unsigned)(p + HALF), o0, o1);
    idx_sample[li * SEQ * NSAMP + p]        = (int)(o0 & (SEQ - 1));
    idx_sample[li * SEQ * NSAMP + p + HALF] = (int)(o1 & (SEQ - 1));
}

// ---------------- input layernorm over C_IN=32 ----------------
__global__ __launch_bounds__(256) void ln_in_kernel(const float* __restrict__ x,
        const float* __restrict__ g, const float* __restrict__ b,
        float* __restrict__ out) {
    int t = blockIdx.x * blockDim.x + threadIdx.x;
    if (t >= TOK) return;
    const float* xr = x + (size_t)t * CIN;
    float vals[CIN];
    float s = 0.f;
#pragma unroll
    for (int c = 0; c < CIN; c++) { vals[c] = xr[c]; s += vals[c]; }
    float m = s * (1.f / CIN);
    float v = 0.f;
#pragma unroll
    for (int c = 0; c < CIN; c++) { float d = vals[c] - m; v += d * d; }
    v *= (1.f / CIN);
    float inv = rsqrtf(v + EPS);
    float* orow = out + (size_t)t * CIN;
#pragma unroll
    for (int c = 0; c < CIN; c++) orow[c] = (vals[c] - m) * inv * g[c] + b[c];
}

// ---------------- im2col (wrap pad), fp32: A[t][j], j=w*32+c ----------------
__global__ __launch_bounds__(128) void im2col_kernel(const float* __restrict__ xln,
        float* __restrict__ a) {
    int t = blockIdx.x;
    int j = threadIdx.x;
    if (j >= 96) return;
    int b = t >> 11, l = t & 2047;
    int w = j >> 5, c = j & 31;
    int lw = (l - 1 + w + SEQ) & 2047;
    a[(size_t)t * 96 + j] = xln[(((size_t)b << 11) | lw) * CIN + c];
}

// ---------------- W_tok transpose + split to interleaved u32: wt[o][j] ----------------
__global__ __launch_bounds__(256) void wtok_split(const float* __restrict__ Wtok,
        u32* __restrict__ wt) {
    int e = blockIdx.x * 256 + threadIdx.x;  // < 49152
    int o = e / 96, j = e % 96;
    float f = Wtok[(size_t)j * DM + o];
    u16 hb = bf16rn(f);
    u16 lb = bf16rn(f - __uint_as_float((u32)hb << 16));
    wt[e] = (u32)hb | ((u32)lb << 16);
}

// ---------------- positional embedding table pe[l][o] ----------------
__global__ __launch_bounds__(256) void pe_kernel(float* __restrict__ pe) {
    int e = blockIdx.x * 256 + threadIdx.x;  // < 1048576
    int l = e >> 9, o = e & 511;
    const float c1 = -0.017988946039016f;  // -ln(10000)/512
    int i2 = o & ~1;
    float div = expf((float)i2 * c1);
    float arg = (float)l * div;
    pe[e] = (o & 1) ? cosf(arg) : sinf(arg);
}

// ---------------- rsd[t][o] = pe[l][o] + tf[t]·Wtime[o] ----------------
__global__ __launch_bounds__(256) void rsd_kernel(const float* __restrict__ pe,
        const float* __restrict__ tfeat, const float* __restrict__ Wtime,
        float* __restrict__ rsd) {
    int t = blockIdx.x, tid = threadIdx.x;
    int l = t & 2047;
    float t0 = tfeat[(size_t)t * 4], t1 = tfeat[(size_t)t * 4 + 1];
    float t2 = tfeat[(size_t)t * 4 + 2], t3 = tfeat[(size_t)t * 4 + 3];
    for (int o = tid; o < DM; o += 256) {
        rsd[(size_t)t * DM + o] = pe[l * DM + o]
            + t0 * Wtime[o * 4] + t1 * Wtime[o * 4 + 1]
            + t2 * Wtime[o * 4 + 2] + t3 * Wtime[o * 4 + 3];
    }
}

// ---------------- weight split: fp32 -> interleaved (bf16_h | bf16_l<<16) ----------------
__global__ __launch_bounds__(256) void split_weights(const float* __restrict__ Wq,
        const float* __restrict__ Wk, const float* __restrict__ Wv,
        const float* __restrict__ Wo, const float* __restrict__ W1,
        const float* __restrict__ W2, u32* __restrict__ out) {
    int i = blockIdx.x * 256 + threadIdx.x;  // < 3145728
    const float* src; int off;
    if (i < 1048576) {
        src = (i < 262144) ? Wq : (i < 524288) ? Wk : (i < 786432) ? Wv : Wo;
        off = i & 262143;
    } else if (i < 2097152) { src = W1; off = i - 1048576; }
    else { src = W2; off = i - 2097152; }
    float f = src[off];
    u16 h = bf16rn(f);
    u16 l = bf16rn(f - __uint_as_float((u32)h << 16));
    out[i] = (u32)h | ((u32)l << 16);
}

__global__ void concat_bias(const float* __restrict__ bq, const float* __restrict__ bk,
                            const float* __restrict__ bv, float* __restrict__ o) {
    int i = blockIdx.x * 256 + threadIdx.x;  // < 1536
    o[i] = (i < 512) ? bq[i] : (i < 1024) ? bk[i - 512] : bv[i - 1024];
}

// ---------------- split-bf16 MFMA GEMM, double-buffered single-barrier K-loop ----------
// C = A[MxK]*W[NxK]^T + bias (+res)(+relu).  A: fp32 split on the fly; Wp: (h|l<<16) u32.
// Iter k: barrier drains W-DMA/A-loads issued at iter k-1 (a full MFMA phase ago).
template<bool RELU, bool RES>
__global__ __launch_bounds__(256, 2) void gemm_split(const float* __restrict__ A,
        const u32* __restrict__ Wp, const float* __restrict__ bias,
        const float* __restrict__ Rsd, float* __restrict__ C,
        int ldc, int K, int lda) {
    __shared__ alignas(16) u16 AhS[2][128 * 40];   // padded stride 40
    __shared__ alignas(16) u16 AlS[2][128 * 40];
    __shared__ alignas(16) u32 Wt[2][4 * 128 * 8]; // [kchunk8][row][8 words]
    const int tid = threadIdx.x;
    const int m0 = blockIdx.y * 128, n0 = blockIdx.x * 128;
    const int lane = tid & 63, wv = tid >> 6;
    const int wm = wv >> 1, wn = wv & 1;
    const int fr = lane & 15, q = lane >> 4;

    floatx4 acc[4][4] = {};

    const int arow = tid >> 1, ahalf = tid & 1;
    const float* abase = A + (size_t)(m0 + arow) * lda + ahalf * 16;
    const u32* wbase = Wp + (size_t)(n0 + (tid >> 1)) * K + (tid & 1) * 4;
    const int wdoff = tid * 16;                 // byte offset in W buf
    const int aoff = arow * 40 + ahalf * 16;

    const int nk = K >> 5;
    float f[16];

    // ---- prologue: stage tile 0 into buf 0, prefetch A tile 1 regs ----
#pragma unroll
    for (int i = 0; i < 4; i++)
        async16(wbase + i * 8, (char*)Wt[0] + wdoff + i * 4096);
    *(float4*)&f[0]  = *(const float4*)(abase);
    *(float4*)&f[4]  = *(const float4*)(abase + 4);
    *(float4*)&f[8]  = *(const float4*)(abase + 8);
    *(float4*)&f[12] = *(const float4*)(abase + 12);
    {
        short8 h0, h1, l0, l1;
#pragma unroll
        for (int j = 0; j < 8; j++) {
            u16 hb = bf16rn(f[j]);
            float r = f[j] - __uint_as_float((u32)hb << 16);
            h0[j] = (short)hb; l0[j] = (short)bf16rn(r);
            u16 hb2 = bf16rn(f[j + 8]);
            float r2 = f[j + 8] - __uint_as_float((u32)hb2 << 16);
            h1[j] = (short)hb2; l1[j] = (short)bf16rn(r2);
        }
        *(short8*)&AhS[0][aoff] = h0;  *(short8*)&AhS[0][aoff + 8] = h1;
        *(short8*)&AlS[0][aoff] = l0;  *(short8*)&AlS[0][aoff + 8] = l1;
    }
    {
        int k1 = (nk > 1) ? 32 : 0;
        const float* ap = abase + k1;
        *(float4*)&f[0]  = *(const float4*)(ap);
        *(float4*)&f[4]  = *(const float4*)(ap + 4);
        *(float4*)&f[8]  = *(const float4*)(ap + 8);
        *(float4*)&f[12] = *(const float4*)(ap + 12);
    }

    for (int k = 0; k < nk; k++) {
        const int b = k & 1;
        __syncthreads();   // buf b fully staged (W-DMA k + A LDS writes); drains last iter's vmem
        if (k + 1 < nk) {
            // issue W DMA for tile k+1 first — lands during converts + MFMA below
            int k0n = (k + 1) << 5;
#pragma unroll
            for (int i = 0; i < 4; i++)
                async16(wbase + k0n + i * 8, (char*)Wt[b ^ 1] + wdoff + i * 4096);
            // convert A tile k+1 (regs) -> LDS buf b^1
            short8 h0, h1, l0, l1;
#pragma unroll
            for (int j = 0; j < 8; j++) {
                u16 hb = bf16rn(f[j]);
                float r = f[j] - __uint_as_float((u32)hb << 16);
                h0[j] = (short)hb; l0[j] = (short)bf16rn(r);
                u16 hb2 = bf16rn(f[j + 8]);
                float r2 = f[j + 8] - __uint_as_float((u32)hb2 << 16);
                h1[j] = (short)hb2; l1[j] = (short)bf16rn(r2);
            }
            *(short8*)&AhS[b ^ 1][aoff] = h0;  *(short8*)&AhS[b ^ 1][aoff + 8] = h1;
            *(short8*)&AlS[b ^ 1][aoff] = l0;  *(short8*)&AlS[b ^ 1][aoff + 8] = l1;
            // prefetch A regs for tile k+2 (clamped)
            int k0nn = (k + 2 < nk) ? ((k + 2) << 5) : 0;
            const float* ap = abase + k0nn;
            *(float4*)&f[0]  = *(const float4*)(ap);
            *(float4*)&f[4]  = *(const float4*)(ap + 4);
            *(float4*)&f[8]  = *(const float4*)(ap + 8);
            *(float4*)&f[12] = *(const float4*)(ap + 12);
        }
        // ---- MFMA on buf b ----
        short8 ah[4], al[4];
#pragma unroll
        for (int mi = 0; mi < 4; mi++) {
            int off = (wm * 64 + mi * 16 + fr) * 40 + q * 8;
            ah[mi] = *(const short8*)&AhS[b][off];
            al[mi] = *(const short8*)&AlS[b][off];
        }
#pragma unroll
        for (int ni = 0; ni < 4; ni++) {
            const u32* cell = &Wt[b][(size_t)(q * 128 + wn * 64 + ni * 16 + fr) * 8];
            union { u32 u[4]; short8 s; } wh, wl;
            u32 w0 = cell[0], w1 = cell[1], w2 = cell[2], w3 = cell[3];
            u32 w4 = cell[4], w5 = cell[5], w6 = cell[6], w7 = cell[7];
            wh.u[0] = (w0 & 0xffffu) | (w1 << 16);
            wh.u[1] = (w2 & 0xffffu) | (w3 << 16);
            wh.u[2] = (w4 & 0xffffu) | (w5 << 16);
            wh.u[3] = (w6 & 0xffffu) | (w7 << 16);
            wl.u[0] = (w0 >> 16) | (w1 & 0xffff0000u);
            wl.u[1] = (w2 >> 16) | (w3 & 0xffff0000u);
            wl.u[2] = (w4 >> 16) | (w5 & 0xffff0000u);
            wl.u[3] = (w6 >> 16) | (w7 & 0xffff0000u);
#pragma unroll
            for (int mi = 0; mi < 4; mi++) {
                acc[mi][ni] = __builtin_amdgcn_mfma_f32_16x16x32_bf16(ah[mi], wh.s, acc[mi][ni], 0, 0, 0);
                acc[mi][ni] = __builtin_amdgcn_mfma_f32_16x16x32_bf16(ah[mi], wl.s, acc[mi][ni], 0, 0, 0);
                acc[mi][ni] = __builtin_amdgcn_mfma_f32_16x16x32_bf16(al[mi], wh.s, acc[mi][ni], 0, 0, 0);
            }
        }
    }
    // --- epilogue ---
#pragma unroll
    for (int ni = 0; ni < 4; ni++) {
        int col = n0 + wn * 64 + ni * 16 + fr;
        float bv = bias[col];
#pragma unroll
        for (int mi = 0; mi < 4; mi++) {
            int row = m0 + wm * 64 + mi * 16 + q * 4;
#pragma unroll
            for (int r = 0; r < 4; r++) {
                size_t idx = (size_t)(row + r) * ldc + col;
                float v = acc[mi][ni][r] + bv;
                if (RES) v += Rsd[idx];
                if (RELU) v = fmaxf(v, 0.f);
                C[idx] = v;
            }
        }
    }
}

// ---------------- M = max(QK_sample) - sum/L : one wave per (b,h,l) ----------------
__global__ __launch_bounds__(256) void qk_sample_kernel(const float* __restrict__ qkv,
        const int* __restrict__ idx_sample, float* __restrict__ Mout) {
    int r = (blockIdx.x * 256 + threadIdx.x) >> 6;
    int lane = threadIdx.x & 63;
    if (r >= BATCH * NH * SEQ) return;
    int b = r / (NH * SEQ);
    int head = (r / SEQ) % NH;
    int l = r % SEQ;
    int sidx = lane >> 4, dc = lane & 15;
    const float* qrow = qkv + ((size_t)(b * SEQ + l)) * QKVLD + head * HD + dc * 4;
    float4 qf = *(const float4*)qrow;
    int myidx = (lane < NSAMP) ? idx_sample[l * NSAMP + lane] : 0;
    const float* kbase = qkv + (size_t)b * SEQ * QKVLD + 512 + head * HD + dc * 4;
    float mx = -INFINITY, sm = 0.f;
#pragma unroll
    for (int p = 0; p < 6; p++) {
        int s = p * 4 + sidx;
        int kidx = __shfl(myidx, s);
        float4 kf = *(const float4*)(kbase + (size_t)kidx * QKVLD);
        float part = qf.x * kf.x + qf.y * kf.y + qf.z * kf.z + qf.w * kf.w;
        part += __shfl_xor(part, 1);
        part += __shfl_xor(part, 2);
        part += __shfl_xor(part, 4);
        part += __shfl_xor(part, 8);
        mx = fmaxf(mx, part);
        sm += part;
    }
    mx = fmaxf(mx, __shfl_xor(mx, 16));
    mx = fmaxf(mx, __shfl_xor(mx, 32));
    sm += __shfl_xor(sm, 16);
    sm += __shfl_xor(sm, 32);
    if (lane == 0) Mout[r] = mx - sm * (1.f / SEQ);
}

// ---------------- top-24 two-stage: packed u64 keys, exact (idx unique) ----------------
__device__ __forceinline__ u64 pack_key(float v, int idx) {
    u32 u = __float_as_uint(v);
    u32 m = (u & 0x80000000u) ? ~u : (u | 0x80000000u);
    return ((u64)m << 32) | (u32)(~(u32)idx);
}

__global__ __launch_bounds__(256) void topk_part(const float* __restrict__ Mbuf,
        u64* __restrict__ cand) {
    __shared__ u64 vals[256];
    __shared__ u64 red[256];
    int bh = blockIdx.x, chunk = blockIdx.y;
    int tid = threadIdx.x;
    int l = chunk * 256 + tid;
    vals[tid] = pack_key(Mbuf[(size_t)bh * SEQ + l], l);
    __syncthreads();
    for (int it = 0; it < NTOP; it++) {
        red[tid] = vals[tid];
        __syncthreads();
        for (int s = 128; s > 0; s >>= 1) {
            if (tid < s) { u64 o = red[tid + s]; if (o > red[tid]) red[tid] = o; }
            __syncthreads();
        }
        u64 win = red[0];
        if (vals[tid] == win) vals[tid] = 0;
        if (tid == 0) cand[((size_t)bh * 8 + chunk) * NTOP + it] = win;
        __syncthreads();
    }
}

__global__ __launch_bounds__(256) void topk_merge(const u64* __restrict__ cand,
        int* __restrict__ idx_top) {
    __shared__ u64 vals[256];
    __shared__ u64 red[256];
    int bh = blockIdx.x;
    int tid = threadIdx.x;
    vals[tid] = (tid < 8 * NTOP) ? cand[(size_t)bh * 8 * NTOP + tid] : 0;
    __syncthreads();
    for (int it = 0; it < NTOP; it++) {
        red[tid] = vals[tid];
        __syncthreads();
        for (int s = 128; s > 0; s >>= 1) {
            if (tid < s) { u64 o = red[tid + s]; if (o > red[tid]) red[tid] = o; }
            __syncthreads();
        }
        u64 win = red[0];
        if (vals[tid] == win) vals[tid] = 0;
        if (tid == 0) idx_top[bh * NTOP + it] = (int)(~(u32)(win & 0xffffffffull) & (SEQ - 1));
        __syncthreads();
    }
}

// ---------------- V mean over keys per (b,h) ----------------
__global__ __launch_bounds__(256) void vmean_kernel(const float* __restrict__ qkv,
        float* __restrict__ vmean) {
    __shared__ float red[256];
    int bh = blockIdx.x, slab = blockIdx.y;
    int b = bh >> 3, head = bh & 7;
    int seg = threadIdx.x >> 6, d = threadIdx.x & 63;
    int base_row = slab * 256 + seg * 64;
    float s = 0.f;
    for (int r = 0; r < 64; r++)
        s += qkv[((size_t)(b * SEQ + base_row + r)) * QKVLD + 1024 + head * HD + d];
    red[threadIdx.x] = s;
    __syncthreads();
    if (threadIdx.x < 128) red[threadIdx.x] += red[threadIdx.x + 128];
    __syncthreads();
    if (threadIdx.x < 64) {
        float t = red[threadIdx.x] + red[threadIdx.x + 64];
        atomicAdd(&vmean[bh * HD + d], t * (1.f / SEQ));
    }
}

// ---------------- fill context with V-mean ----------------
__global__ void fillctx_kernel(const float* __restrict__ vmean, float* __restrict__ out) {
    int e = blockIdx.x * 256 + threadIdx.x;
    int c = e & 511;
    int b = e >> 20;
    out[e] = vmean[(((b << 3) | (c >> 6)) << 6) + (c & 63)];
}

// ---------------- flash-style sparse attention: block = (b*h, key-slab of 512) ----------------
__global__ __launch_bounds__(256) void spattn_flash(const float* __restrict__ qkv,
        const int* __restrict__ idx_top, float* __restrict__ opart,
        float* __restrict__ mspart) {
    __shared__ float KtT[64][65];   // transposed: [dim][key]
    __shared__ float Vt[64][65];    // [key][dim]
    __shared__ float Qs[24][64];
    __shared__ float Ps[24][66];
    int bh = blockIdx.x, slab = blockIdx.y;
    int b = bh >> 3, h = bh & 7;
    int tid = threadIdx.x;
    int wv = tid >> 6, lane = tid & 63;
    for (int i = tid; i < NTOP * 64; i += 256) {
        int u = i >> 6, d = i & 63;
        int qi = idx_top[bh * NTOP + u];
        Qs[u][d] = qkv[((size_t)(b * SEQ + qi)) * QKVLD + h * HD + d];
    }
    float m[6], s[6], o[6], alpha[6];
#pragma unroll
    for (int j = 0; j < 6; j++) { m[j] = -INFINITY; s[j] = 0.f; o[j] = 0.f; }
    int key0 = slab * 512;
    int sr = tid >> 2, sc0 = (tid & 3) * 16;
    for (int t = 0; t < 8; t++) {
        int kbase = key0 + t * 64;
        __syncthreads();
        const float* kr = qkv + ((size_t)(b * SEQ + kbase + sr)) * QKVLD + 512 + h * HD + sc0;
        const float* vr = qkv + ((size_t)(b * SEQ + kbase + sr)) * QKVLD + 1024 + h * HD + sc0;
        float kf[16], vf[16];
        *(float4*)&kf[0]  = *(const float4*)(kr);
        *(float4*)&kf[4]  = *(const float4*)(kr + 4);
        *(float4*)&kf[8]  = *(const float4*)(kr + 8);
        *(float4*)&kf[12] = *(const float4*)(kr + 12);
        *(float4*)&vf[0]  = *(const float4*)(vr);
        *(float4*)&vf[4]  = *(const float4*)(vr + 4);
        *(float4*)&vf[8]  = *(const float4*)(vr + 8);
        *(float4*)&vf[12] = *(const float4*)(vr + 12);
#pragma unroll
        for (int i = 0; i < 16; i++) {
            KtT[sc0 + i][sr] = kf[i];
            Vt[sr][sc0 + i] = vf[i];
        }
        __syncthreads();
        float dot[6] = {};
#pragma unroll
        for (int d = 0; d < 64; d++) {
            float kv = KtT[d][lane];
#pragma unroll
            for (int j = 0; j < 6; j++) dot[j] += Qs[wv * 6 + j][d] * kv;
        }
#pragma unroll
        for (int j = 0; j < 6; j++) {
            float sc = dot[j] * 0.125f;
            float tmax = sc;
            for (int off = 32; off > 0; off >>= 1) tmax = fmaxf(tmax, __shfl_xor(tmax, off));
            float mn = fmaxf(m[j], tmax);
            float p = __expf(sc - mn);
            float psum = p;
            for (int off = 32; off > 0; off >>= 1) psum += __shfl_xor(psum, off);
            alpha[j] = __expf(m[j] - mn);
            s[j] = s[j] * alpha[j] + psum;
            m[j] = mn;
            Ps[wv * 6 + j][lane] = p;
        }
        float pv[6] = {};
#pragma unroll
        for (int key = 0; key < 64; key++) {
            float vvv = Vt[key][lane];
#pragma unroll
            for (int j = 0; j < 6; j++) pv[j] += Ps[wv * 6 + j][key] * vvv;
        }
#pragma unroll
        for (int j = 0; j < 6; j++) o[j] = o[j] * alpha[j] + pv[j];
    }
    float* ob = opart + ((size_t)(bh * 4 + slab)) * NTOP * 64;
#pragma unroll
    for (int j = 0; j < 6; j++) ob[(wv * 6 + j) * 64 + lane] = o[j];
    if (lane == 0) {
        float* ms = mspart + ((size_t)(bh * 4 + slab)) * NTOP * 2;
#pragma unroll
        for (int j = 0; j < 6; j++) {
            ms[(wv * 6 + j) * 2]     = m[j];
            ms[(wv * 6 + j) * 2 + 1] = s[j];
        }
    }
}

// ---------------- merge 4 slab partials, scatter into context ----------------
__global__ __launch_bounds__(256) void spattn_combine(const float* __restrict__ opart,
        const float* __restrict__ mspart, const int* __restrict__ idx_top,
        float* __restrict__ out) {
    __shared__ float wgt[4][NTOP];
    int bh = blockIdx.x;
    int b = bh >> 3, h = bh & 7;
    int tid = threadIdx.x;
    if (tid < NTOP) {
        float mv[4], sv[4];
        float M = -INFINITY;
#pragma unroll
        for (int sl = 0; sl < 4; sl++) {
            mv[sl] = mspart[((size_t)(bh * 4 + sl)) * NTOP * 2 + tid * 2];
            sv[sl] = mspart[((size_t)(bh * 4 + sl)) * NTOP * 2 + tid * 2 + 1];
            M = fmaxf(M, mv[sl]);
        }
        float S = 0.f;
#pragma unroll
        for (int sl = 0; sl < 4; sl++) S += sv[sl] * __expf(mv[sl] - M);
        float invS = 1.f / S;
#pragma unroll
        for (int sl = 0; sl < 4; sl++) wgt[sl][tid] = __expf(mv[sl] - M) * invS;
    }
    __syncthreads();
    for (int i = tid; i < NTOP * 64; i += 256) {
        int u = i >> 6, d = i & 63;
        float val = 0.f;
#pragma unroll
        for (int sl = 0; sl < 4; sl++)
            val += wgt[sl][u] * opart[(((size_t)(bh * 4 + sl)) * NTOP + u) * 64 + d];
        int qi = idx_top[bh * NTOP + u];
        out[((size_t)(b * SEQ + qi)) * DM + h * HD + d] = val;
    }
}

// ---------------- layernorm over DM=512 ----------------
__global__ __launch_bounds__(256) void ln_kernel(const float* src,
        const float* __restrict__ g, const float* __restrict__ b, float* dst) {
    __shared__ float red[256];
    int t = blockIdx.x, tid = threadIdx.x;
    const float* xr = src + (size_t)t * DM;
    float x0 = xr[tid], x1 = xr[tid + 256];
    red[tid] = x0 + x1; __syncthreads();
    for (int s = 128; s > 0; s >>= 1) { if (tid < s) red[tid] += red[tid + s]; __syncthreads(); }
    float m = red[0] * (1.f / DM);
    __syncthreads();
    float d0 = x0 - m, d1 = x1 - m;
    red[tid] = d0 * d0 + d1 * d1; __syncthreads();
    for (int s = 128; s > 0; s >>= 1) { if (tid < s) red[tid] += red[tid + s]; __syncthreads(); }
    float inv = rsqrtf(red[0] * (1.f / DM) + EPS);
    float* dr = dst + (size_t)t * DM;
    dr[tid] = d0 * inv * g[tid] + b[tid];
    dr[tid + 256] = d1 * inv * g[tid + 256] + b[tid + 256];
}

// ---------------- prediction head on last token ----------------
__global__ __launch_bounds__(256) void head_kernel(const float* __restrict__ hfin,
        const float* __restrict__ Wpre, const float* __restrict__ bpre,
        const float* __restrict__ Wfc, const float* __restrict__ bfc,
        float* __restrict__ out) {
    __shared__ float last[DM];
    __shared__ float red[256];
    int b = blockIdx.x, tid = threadIdx.x;
    const float* hr = hfin + ((size_t)(b * SEQ + SEQ - 1)) * DM;
    last[tid] = hr[tid];
    last[tid + 256] = hr[tid + 256];
    __syncthreads();
    float acc = bpre[tid];
    for (int c = 0; c < DM; c++) acc += last[c] * Wpre[tid * DM + c];
    acc = fmaxf(acc, 0.f);
    red[tid] = acc * Wfc[tid];
    __syncthreads();
    for (int s = 128; s > 0; s >>= 1) { if (tid < s) red[tid] += red[tid + s]; __syncthreads(); }
    if (tid == 0) out[b] = red[0] + bfc[0];
}

extern "C" void kernel_launch(void* const* d_in, const int* in_sizes, int n_in,
                              void* d_out, int out_size, void* d_ws, size_t ws_size,
                              hipStream_t stream) {
    (void)in_sizes; (void)n_in; (void)out_size; (void)ws_size;
    const float* x      = (const float*)d_in[0];
    const float* tfeat  = (const float*)d_in[1];
    const float* g_in   = (const float*)d_in[2];
    const float* b_in   = (const float*)d_in[3];
    const float* W_tok  = (const float*)d_in[4];
    const float* W_time = (const float*)d_in[5];
    const float* b_time = (const float*)d_in[6];
    const float* Wq     = (const float*)d_in[7];
    const float* bq     = (const float*)d_in[8];
    const float* Wk     = (const float*)d_in[9];
    const float* bk     = (const float*)d_in[10];
    const float* Wv     = (const float*)d_in[11];
    const float* bv     = (const float*)d_in[12];
    const float* Wo     = (const float*)d_in[13];
    const float* bo     = (const float*)d_in[14];
    const float* W1     = (const float*)d_in[15];
    const float* b1     = (const float*)d_in[16];
    const float* W2     = (const float*)d_in[17];
    const float* b2     = (const float*)d_in[18];
    const float* g1     = (const float*)d_in[19];
    const float* be1    = (const float*)d_in[20];
    const float* g2     = (const float*)d_in[21];
    const float* be2    = (const float*)d_in[22];
    const float* g_enc  = (const float*)d_in[23];
    const float* b_enc  = (const float*)d_in[24];
    const float* W_pre  = (const float*)d_in[25];
    const float* b_pre  = (const float*)d_in[26];
    const float* W_fc   = (const float*)d_in[27];
    const float* b_fc   = (const float*)d_in[28];
    float* out = (float*)d_out;

    char* ws = (char*)d_ws;
    float* h    = (float*)(ws);                      // 33.5 MB fp32 residual
    float* tmp  = (float*)(ws + 33554432);           // 33.5 MB fp32
    char*  bigc = ws + 67108864;                     // 134.2 MB multi-use
    float* big  = (float*)bigc;                      // qkv [TOK][1536] fp32 / FFN mid
    // embed-stage overlays inside big:
    float* xln  = (float*)(bigc);                    // 2 MB
    float* acv  = (float*)(bigc + 2097152);          // im2col [TOK][96] fp32, 6.3 MB
    float* pe   = (float*)(bigc + 8388608);          // 4 MB
    float* rsd  = (float*)(bigc + 12582912);         // 33.5 MB
    u32*   wtok = (u32*)(bigc + 46137344);           // W_tok interleaved [512][96]
    u32*   wpair      = (u32*)(ws + 201326592);      // 12.6 MB per-layer weights
    float* Mbuf       = (float*)(ws + 213909504);    // 0.5 MB
    float* vmean      = (float*)(ws + 214433792);
    int*   idx_sample = (int*)(ws + 214450176);
    int*   idx_top    = (int*)(ws + 214843392);
    float* biasqkv    = (float*)(ws + 214849536);
    u64*   cand       = (u64*)(ws + 214855680);      // 98 KB
    float* opart      = (float*)(ws + 214953984);    // 1.57 MB
    float* mspart     = (float*)(ws + 216526848);    // 48 KB

    ln_in_kernel<<<TOK / 256, 256, 0, stream>>>(x, g_in, b_in, xln);
    im2col_kernel<<<TOK, 128, 0, stream>>>(xln, acv);
    wtok_split<<<192, 256, 0, stream>>>(W_tok, wtok);
    pe_kernel<<<4096, 256, 0, stream>>>(pe);
    rsd_kernel<<<TOK, 256, 0, stream>>>(pe, tfeat, W_time, rsd);
    sample_kernel<<<dim3(96, 2), 256, 0, stream>>>(idx_sample);

    // conv-as-GEMM: h = im2col @ W_tok^T + b_time + (pe + time emb)
    gemm_split<false, true><<<dim3(4, 128), 256, 0, stream>>>(
        acv, wtok, b_time, rsd, h, DM, 96, 96);

    const u32* wqkv_p = wpair;                // rows 0..1535 = Wq;Wk;Wv
    const u32* wo_p = wpair + 786432;
    const u32* w1_p = wpair + 1048576;
    const u32* w2_p = wpair + 2097152;

    for (int li = 0; li < 2; li++) {
        split_weights<<<12288, 256, 0, stream>>>(
            Wq + (size_t)li * DM * DM, Wk + (size_t)li * DM * DM,
            Wv + (size_t)li * DM * DM, Wo + (size_t)li * DM * DM,
            W1 + (size_t)li * DFF * DM, W2 + (size_t)li * DM * DFF, wpair);
        concat_bias<<<6, 256, 0, stream>>>(bq + (size_t)li * DM, bk + (size_t)li * DM,
                                           bv + (size_t)li * DM, biasqkv);

        const float* bo_i = bo + (size_t)li * DM;
        const float* b1_i = b1 + (size_t)li * DFF;
        const float* b2_i = b2 + (size_t)li * DM;
        const float* g1_i = g1 + (size_t)li * DM;
        const float* be1_i = be1 + (size_t)li * DM;
        const float* g2_i = g2 + (size_t)li * DM;
        const float* be2_i = be2 + (size_t)li * DM;

        // fused QKV: [TOK][1536] fp32
        gemm_split<false, false><<<dim3(QKVLD / 128, TOK / 128), 256, 0, stream>>>(
            h, wqkv_p, biasqkv, nullptr, big, QKVLD, DM, DM);

        qk_sample_kernel<<<(BATCH * NH * SEQ) / 4, 256, 0, stream>>>(
            big, idx_sample + li * SEQ * NSAMP, Mbuf);
        topk_part<<<dim3(BATCH * NH, 8), 256, 0, stream>>>(Mbuf, cand);
        topk_merge<<<BATCH * NH, 256, 0, stream>>>(cand, idx_top);
        hipMemsetAsync(vmean, 0, BATCH * NH * HD * sizeof(float), stream);
        vmean_kernel<<<dim3(BATCH * NH, 8), 256, 0, stream>>>(big, vmean);
        fillctx_kernel<<<(TOK * DM) / 256, 256, 0, stream>>>(vmean, tmp);
        spattn_flash<<<dim3(BATCH * NH, 4), 256, 0, stream>>>(big, idx_top, opart, mspart);
        spattn_combine<<<BATCH * NH, 256, 0, stream>>>(opart, mspart, idx_top, tmp);

        // Wo with residual into h
        gemm_split<false, true><<<dim3(DM / 128, TOK / 128), 256, 0, stream>>>(
            tmp, wo_p, bo_i, h, h, DM, DM, DM);
        ln_kernel<<<TOK, 256, 0, stream>>>(h, g1_i, be1_i, h);

        // FFN full-width
        gemm_split<true, false><<<dim3(DFF / 128, TOK / 128), 256, 0, stream>>>(
            h, w1_p, b1_i, nullptr, big, DFF, DM, DM);
        gemm_split<false, true><<<dim3(DM / 128, TOK / 128), 256, 0, stream>>>(
            big, w2_p, b2_i, h, tmp, DM, DFF, DFF);
        ln_kernel<<<TOK, 256, 0, stream>>>(tmp, g2_i, be2_i, h);
    }

    ln_kernel<<<TOK, 256, 0, stream>>>(h, g_enc, b_enc, tmp);
    head_kernel<<<BATCH, 256, 0, stream>>>(tmp, W_pre, b_pre, W_fc, b_fc, out);
}